// Round 14
// baseline (153.982 us; speedup 1.0000x reference)
//
#include <hip/hip_runtime.h>
#include <math.h>

#define N_PTS 131072
#define BPB   16                 // blocks per batch (reduction chunks)
#define CHUNK (N_PTS / BPB)      // 8192 elements per block
#define TPB   1024               // 16 waves/block; 2 blocks/CU -> 32 waves/CU
#define NACC  16                 // W, As[3], At[3], M[9]
#define NITER (CHUNK / 4 / TPB)  // 2 float4 per thread per stream

// clang-native 4-float vector: accepted by __builtin_nontemporal_load
typedef float f4 __attribute__((ext_vector_type(4)));

// ---------------- Kernel 1: streaming partial reduction (NT loads) --------
__global__ __launch_bounds__(TPB) void ego_partial_kernel(
    const float* __restrict__ xyz_s,    // (B,3,N)
    const float* __restrict__ wtgt,     // (B,3,N)
    const float* __restrict__ weights,  // (B,1,N)
    const float* __restrict__ label,    // (B,1,N)
    float* __restrict__ partials)       // (B, BPB, 16)
{
    const int b     = blockIdx.y;
    const int chunk = blockIdx.x;
    const int t     = threadIdx.x;

    const size_t baseN  = (size_t)b * N_PTS + (size_t)chunk * CHUNK;
    const size_t base3  = (size_t)b * 3 * N_PTS + (size_t)chunk * CHUNK;

    const f4* w4  = (const f4*)(weights + baseN);
    const f4* l4  = (const f4*)(label   + baseN);
    const f4* xs0 = (const f4*)(xyz_s + base3);
    const f4* xs1 = (const f4*)(xyz_s + base3 + N_PTS);
    const f4* xs2 = (const f4*)(xyz_s + base3 + 2 * N_PTS);
    const f4* xt0 = (const f4*)(wtgt  + base3);
    const f4* xt1 = (const f4*)(wtgt  + base3 + N_PTS);
    const f4* xt2 = (const f4*)(wtgt  + base3 + 2 * N_PTS);

    float acc[NACC];
#pragma unroll
    for (int i = 0; i < NACC; ++i) acc[i] = 0.0f;

#pragma unroll
    for (int k = 0; k < NITER; ++k) {   // 2 iterations
        const int i = t + k * TPB;
        const f4 wv = __builtin_nontemporal_load(&w4[i]);
        const f4 lv = __builtin_nontemporal_load(&l4[i]);
        const f4 a0 = __builtin_nontemporal_load(&xs0[i]);
        const f4 a1 = __builtin_nontemporal_load(&xs1[i]);
        const f4 a2 = __builtin_nontemporal_load(&xs2[i]);
        const f4 b0 = __builtin_nontemporal_load(&xt0[i]);
        const f4 b1 = __builtin_nontemporal_load(&xt1[i]);
        const f4 b2 = __builtin_nontemporal_load(&xt2[i]);

#define ACCUM(C)                                              \
        {                                                     \
            const float w  = wv.C * fabsf(lv.C - 1.0f);       \
            const float s0 = a0.C, s1 = a1.C, s2 = a2.C;      \
            const float t0 = b0.C, t1 = b1.C, t2 = b2.C;      \
            acc[0] += w;                                      \
            const float ws0 = w * s0, ws1 = w * s1, ws2 = w * s2; \
            acc[1] += ws0;  acc[2] += ws1;  acc[3] += ws2;    \
            acc[4] += w * t0; acc[5] += w * t1; acc[6] += w * t2; \
            acc[7]  += ws0 * t0; acc[8]  += ws0 * t1; acc[9]  += ws0 * t2; \
            acc[10] += ws1 * t0; acc[11] += ws1 * t1; acc[12] += ws1 * t2; \
            acc[13] += ws2 * t0; acc[14] += ws2 * t1; acc[15] += ws2 * t2; \
        }
        ACCUM(x) ACCUM(y) ACCUM(z) ACCUM(w)
#undef ACCUM
    }

    // wave-level reduce (64 lanes)
#pragma unroll
    for (int i = 0; i < NACC; ++i) {
        float v = acc[i];
#pragma unroll
        for (int off = 32; off > 0; off >>= 1)
            v += __shfl_down(v, off, 64);
        acc[i] = v;
    }

    __shared__ float red[TPB / 64][NACC];   // 16 x 16 floats = 1 KB
    const int wave = t >> 6;
    const int lane = t & 63;
    if (lane == 0) {
#pragma unroll
        for (int i = 0; i < NACC; ++i) red[wave][i] = acc[i];
    }
    __syncthreads();

    if (t < NACC) {
        float v = 0.0f;
#pragma unroll
        for (int wv_ = 0; wv_ < TPB / 64; ++wv_) v += red[wv_][t];
        partials[((size_t)b * BPB + chunk) * NACC + t] = v;
    }
}

// ---------------- Kernel 2: final reduce + scratch-free 3x3 SVD ----------
__global__ __launch_bounds__(64) void ego_finalize_kernel(
    const float* __restrict__ partials,  // (B, BPB, 16)
    float* __restrict__ out,             // rot (B,3,3) then translation (B,3,1)
    int B)
{
    const int b = blockIdx.x;
    const int t = threadIdx.x;   // 0..63; only t<BPB carry data

    double acc[NACC];
#pragma unroll
    for (int i = 0; i < NACC; ++i) acc[i] = 0.0;
    if (t < BPB) {
        const float* p = partials + ((size_t)b * BPB + t) * NACC;
#pragma unroll
        for (int i = 0; i < NACC; ++i) acc[i] = (double)p[i];
    }

#pragma unroll
    for (int i = 0; i < NACC; ++i) {
        double v = acc[i];
#pragma unroll
        for (int off = 32; off > 0; off >>= 1)
            v += __shfl_down(v, off, 64);
        acc[i] = v;
    }

    if (t != 0) return;

    // ---- all-scalar solve: no arrays, no dynamic indexing, no scratch ----
    const double W     = acc[0];
    const double denom = W + 1e-6;
    const double cs0 = acc[1] / denom, cs1 = acc[2] / denom, cs2 = acc[3] / denom;
    const double ct0 = acc[4] / denom, ct1 = acc[5] / denom, ct2 = acc[6] / denom;
    const double f   = 2.0 - W / denom;

    const double c00 = acc[7]  / denom - cs0 * ct0 * f;
    const double c01 = acc[8]  / denom - cs0 * ct1 * f;
    const double c02 = acc[9]  / denom - cs0 * ct2 * f;
    const double c10 = acc[10] / denom - cs1 * ct0 * f;
    const double c11 = acc[11] / denom - cs1 * ct1 * f;
    const double c12 = acc[12] / denom - cs1 * ct2 * f;
    const double c20 = acc[13] / denom - cs2 * ct0 * f;
    const double c21 = acc[14] / denom - cs2 * ct1 * f;
    const double c22 = acc[15] / denom - cs2 * ct2 * f;

    // Bm = cov^T cov (symmetric, 6 scalars)
    double b00 = c00*c00 + c10*c10 + c20*c20;
    double b01 = c00*c01 + c10*c11 + c20*c21;
    double b02 = c00*c02 + c10*c12 + c20*c22;
    double b11 = c01*c01 + c11*c11 + c21*c21;
    double b12 = c01*c02 + c11*c12 + c21*c22;
    double b22 = c02*c02 + c12*c12 + c22*c22;

    double v00 = 1, v01 = 0, v02 = 0;
    double v10 = 0, v11 = 1, v12 = 0;
    double v20 = 0, v21 = 0, v22 = 1;

#define JROT(bpp, bqq, bpq, bkp, bkq, vp0, vp1, vp2, vq0, vq1, vq2)   \
    if (fabs(bpq) > 1e-30) {                                          \
        const double tau = (bqq - bpp) / (2.0 * bpq);                 \
        const double jt  = (tau >= 0.0 ? 1.0 : -1.0) /                \
                           (fabs(tau) + sqrt(1.0 + tau * tau));       \
        const double jc  = 1.0 / sqrt(1.0 + jt * jt);                 \
        const double js  = jt * jc;                                   \
        bpp -= jt * bpq; bqq += jt * bpq; bpq = 0.0;                  \
        { const double kp = bkp, kq = bkq;                            \
          bkp = jc * kp - js * kq; bkq = js * kp + jc * kq; }         \
        { double x;                                                   \
          x = vp0; vp0 = jc * x - js * vq0; vq0 = js * x + jc * vq0;  \
          x = vp1; vp1 = jc * x - js * vq1; vq1 = js * x + jc * vq1;  \
          x = vp2; vp2 = jc * x - js * vq2; vq2 = js * x + jc * vq2; }\
    }

#pragma unroll
    for (int sweep = 0; sweep < 6; ++sweep) {
        JROT(b00, b11, b01, b02, b12, v00, v10, v20, v01, v11, v21)
        JROT(b00, b22, b02, b01, b12, v00, v10, v20, v02, v12, v22)
        JROT(b11, b22, b12, b01, b02, v01, v11, v21, v02, v12, v22)
    }
#undef JROT

    double l0 = b00, l1 = b11, l2 = b22;
#define CSWAP(la, lb, a0, a1, a2, q0, q1, q2)                         \
    if (lb > la) { double x;                                          \
        x = la; la = lb; lb = x;                                      \
        x = a0; a0 = q0; q0 = x;                                      \
        x = a1; a1 = q1; q1 = x;                                      \
        x = a2; a2 = q2; q2 = x; }
    CSWAP(l0, l1, v00, v10, v20, v01, v11, v21)
    CSWAP(l0, l2, v00, v10, v20, v02, v12, v22)
    CSWAP(l1, l2, v01, v11, v21, v02, v12, v22)
#undef CSWAP

#define MAKEU(vc0, vc1, vc2, u0, u1, u2)                              \
    double u0 = c00 * vc0 + c01 * vc1 + c02 * vc2;                    \
    double u1 = c10 * vc0 + c11 * vc1 + c12 * vc2;                    \
    double u2 = c20 * vc0 + c21 * vc1 + c22 * vc2;                    \
    { const double nn = sqrt(u0 * u0 + u1 * u1 + u2 * u2);            \
      const double r = (nn > 1e-150) ? 1.0 / nn : 0.0;                \
      u0 *= r; u1 *= r; u2 *= r; }
    MAKEU(v00, v10, v20, u00, u10, u20)
    MAKEU(v01, v11, v21, u01, u11, u21)
    MAKEU(v02, v12, v22, u02, u12, u22)
#undef MAKEU
    if (u02 * u02 + u12 * u12 + u22 * u22 < 0.5) {
        u02 = u10 * u21 - u20 * u11;
        u12 = u20 * u01 - u00 * u21;
        u22 = u00 * u11 - u10 * u01;
    }

    const double a00_ = v00*u00 + v01*u01, g00 = v02*u02;
    const double a01_ = v00*u10 + v01*u11, g01 = v02*u12;
    const double a02_ = v00*u20 + v01*u21, g02 = v02*u22;
    const double a10_ = v10*u00 + v11*u01, g10 = v12*u02;
    const double a11_ = v10*u10 + v11*u11, g11 = v12*u12;
    const double a12_ = v10*u20 + v11*u21, g12 = v12*u22;
    const double a20_ = v20*u00 + v21*u01, g20 = v22*u02;
    const double a21_ = v20*u10 + v21*u11, g21 = v22*u12;
    const double a22_ = v20*u20 + v21*u21, g22 = v22*u22;

    const double r00 = a00_ + g00, r01 = a01_ + g01, r02 = a02_ + g02;
    const double r10 = a10_ + g10, r11 = a11_ + g11, r12 = a12_ + g12;
    const double r20 = a20_ + g20, r21 = a21_ + g21, r22 = a22_ + g22;
    const double det = r00 * (r11 * r22 - r12 * r21)
                     - r01 * (r10 * r22 - r12 * r20)
                     + r02 * (r10 * r21 - r11 * r20);
    const double sgn = (det > 0.0) ? 1.0 : -1.0;

    const double R00 = a00_ + sgn * g00, R01 = a01_ + sgn * g01, R02 = a02_ + sgn * g02;
    const double R10 = a10_ + sgn * g10, R11 = a11_ + sgn * g11, R12 = a12_ + sgn * g12;
    const double R20 = a20_ + sgn * g20, R21 = a21_ + sgn * g21, R22 = a22_ + sgn * g22;

    const double t0 = -(R00 * cs0 + R01 * cs1 + R02 * cs2) + ct0;
    const double t1 = -(R10 * cs0 + R11 * cs1 + R12 * cs2) + ct1;
    const double t2 = -(R20 * cs0 + R21 * cs1 + R22 * cs2) + ct2;

    float* ro = out + (size_t)b * 9;
    ro[0] = (float)R00; ro[1] = (float)R01; ro[2] = (float)R02;
    ro[3] = (float)R10; ro[4] = (float)R11; ro[5] = (float)R12;
    ro[6] = (float)R20; ro[7] = (float)R21; ro[8] = (float)R22;
    float* to = out + (size_t)B * 9 + (size_t)b * 3;
    to[0] = (float)t0; to[1] = (float)t1; to[2] = (float)t2;
}

extern "C" void kernel_launch(void* const* d_in, const int* in_sizes, int n_in,
                              void* d_out, int out_size, void* d_ws, size_t ws_size,
                              hipStream_t stream) {
    const float* xyz_s   = (const float*)d_in[0];
    const float* wtgt    = (const float*)d_in[1];
    const float* weights = (const float*)d_in[2];
    const float* label   = (const float*)d_in[3];
    float* out = (float*)d_out;
    float* partials = (float*)d_ws;   // B*BPB*16 floats = 32 KB

    const int B = in_sizes[2] / N_PTS;   // weights has B*N elements

    dim3 grid1(BPB, B);
    ego_partial_kernel<<<grid1, TPB, 0, stream>>>(xyz_s, wtgt, weights, label, partials);
    ego_finalize_kernel<<<B, 64, 0, stream>>>(partials, out, B);
}